// Round 2
// baseline (240.247 us; speedup 1.0000x reference)
//
#include <hip/hip_runtime.h>

// Problem constants (match reference)
#define BB 64
#define LL 1500
#define DD 768
#define TT 240000
#define BIN 160          // TT / LL  (mask words per bin, mask is int32 on device)
#define NCH 25           // L-chunks for deterministic two-stage reduce
#define LCH 60           // LL / NCH
#define TWO_D 1536

// ---------------- workspace layout (bytes) ----------------
#define OFF_VALID   0          // BB*LL floats   (384000 B)
#define OFF_CNT     384000     // BB floats
#define OFF_PARTIAL 384256     // BB*NCH*DD floats (4915200 B)
#define OFF_MEAN    5299456    // BB*DD floats
#define OFF_H       5496064    // BB*TWO_D floats
#define OFF_RAW     5889280    // BB*DD floats

// Kernel 1: valid[bin] = 1.0f iff all 160 mask WORDS (int32 bool) in bin are 0.
// One wave (64 lanes) handles 2 consecutive bins = 320 words; 5 coalesced
// dword loads per lane; OR-reduce across the wave via __ballot (64-bit).
__global__ void k_valid(const unsigned int* __restrict__ mask,
                        float* __restrict__ valid) {
    int gtid = blockIdx.x * blockDim.x + threadIdx.x;
    int wave = gtid >> 6;            // global wave id; wave handles bins 2w, 2w+1
    int lane = gtid & 63;
    size_t base = (size_t)wave * 2 * BIN;   // word offset of bin 2w
    unsigned int a0 = 0u, a1 = 0u;
#pragma unroll
    for (int j = 0; j < 5; ++j) {
        unsigned int w = mask[base + (size_t)j * 64 + lane];
        int widx = j * 64 + lane;
        if (widx < BIN) a0 |= w; else a1 |= w;
    }
    unsigned long long any0 = __ballot(a0 != 0u);
    unsigned long long any1 = __ballot(a1 != 0u);
    if (lane == 0) {
        valid[2 * wave]     = (any0 == 0ull) ? 1.0f : 0.0f;
        valid[2 * wave + 1] = (any1 == 0ull) ? 1.0f : 0.0f;
    }
}

// Kernel 1b: cnt[b] = sum_l valid[b,l]  (one block per b)
__global__ void k_cnt(const float* __restrict__ valid, float* __restrict__ cnt) {
    int b = blockIdx.x;
    float s = 0.0f;
    for (int l = threadIdx.x; l < LL; l += blockDim.x) s += valid[b * LL + l];
    for (int off = 32; off; off >>= 1) s += __shfl_down(s, off);   // wave64 reduce
    __shared__ float sh[4];
    int wave = threadIdx.x >> 6, lane = threadIdx.x & 63;
    if (lane == 0) sh[wave] = s;
    __syncthreads();
    if (threadIdx.x == 0) cnt[b] = sh[0] + sh[1] + sh[2] + sh[3];
}

// Kernel 2: partial[b,c,d] = sum over l in chunk c of valid[b,l]*emb[b,l,d].
// 192 threads/block, each owns 4 consecutive d (float4). Invalid rows are
// skipped entirely (block-uniform branch) -> ~25% HBM fetch saved.
__global__ __launch_bounds__(192) void k_partial(const float* __restrict__ emb,
                                                 const float* __restrict__ valid,
                                                 float* __restrict__ partial) {
    int b = blockIdx.x;
    int c = blockIdx.y;
    int t = threadIdx.x;                 // 0..191 -> d = 4t..4t+3
    int l0 = c * LCH;
    const float* ebase = emb + ((size_t)b * LL + l0) * DD + 4 * t;
    const float* vbase = valid + b * LL + l0;
    float4 acc = {0.f, 0.f, 0.f, 0.f};
    for (int i = 0; i < LCH; ++i) {
        if (vbase[i] != 0.0f) {          // block-uniform branch
            float4 v = *(const float4*)(ebase + (size_t)i * DD);
            acc.x += v.x; acc.y += v.y; acc.z += v.z; acc.w += v.w;
        }
    }
    *(float4*)(partial + ((size_t)(b * NCH + c)) * DD + 4 * t) = acc;
}

// Kernel 3: mean[b,d] = (sum_c partial[b,c,d]) / cnt[b]
__global__ void k_mean(const float* __restrict__ partial,
                       const float* __restrict__ cnt,
                       float* __restrict__ mean) {
    int idx = blockIdx.x * blockDim.x + threadIdx.x;   // b*DD + d
    if (idx >= BB * DD) return;
    int b = idx / DD, d = idx % DD;
    float s = 0.0f;
#pragma unroll 5
    for (int c = 0; c < NCH; ++c) s += partial[((size_t)(b * NCH + c)) * DD + d];
    mean[idx] = s / cnt[b];
}

// Kernel 4: h[b,j] = relu( sum_d mean[b,d] * W1[j,d] ), 4-wide b-tile per thread.
__global__ void k_fc1(const float* __restrict__ mean,
                      const float* __restrict__ W1,
                      float* __restrict__ h) {
    int idx = blockIdx.x * blockDim.x + threadIdx.x;
    int j = idx % TWO_D, g = idx / TWO_D;
    const float4* w  = (const float4*)(W1 + (size_t)j * DD);
    const float4* m0 = (const float4*)(mean + (size_t)(4 * g + 0) * DD);
    const float4* m1 = (const float4*)(mean + (size_t)(4 * g + 1) * DD);
    const float4* m2 = (const float4*)(mean + (size_t)(4 * g + 2) * DD);
    const float4* m3 = (const float4*)(mean + (size_t)(4 * g + 3) * DD);
    float a0 = 0.f, a1 = 0.f, a2 = 0.f, a3 = 0.f;
#pragma unroll 4
    for (int i = 0; i < DD / 4; ++i) {
        float4 wv = w[i];
        float4 v0 = m0[i], v1 = m1[i], v2 = m2[i], v3 = m3[i];
        a0 += wv.x * v0.x + wv.y * v0.y + wv.z * v0.z + wv.w * v0.w;
        a1 += wv.x * v1.x + wv.y * v1.y + wv.z * v1.z + wv.w * v1.w;
        a2 += wv.x * v2.x + wv.y * v2.y + wv.z * v2.z + wv.w * v2.w;
        a3 += wv.x * v3.x + wv.y * v3.y + wv.z * v3.z + wv.w * v3.w;
    }
    h[(4 * g + 0) * TWO_D + j] = fmaxf(a0, 0.f);
    h[(4 * g + 1) * TWO_D + j] = fmaxf(a1, 0.f);
    h[(4 * g + 2) * TWO_D + j] = fmaxf(a2, 0.f);
    h[(4 * g + 3) * TWO_D + j] = fmaxf(a3, 0.f);
}

// Kernel 5: raw[b,d] = sum_j h[b,j] * W2[d,j], 4-wide b-tile per thread.
__global__ void k_fc2(const float* __restrict__ h,
                      const float* __restrict__ W2,
                      float* __restrict__ raw) {
    int idx = blockIdx.x * blockDim.x + threadIdx.x;
    int d = idx % DD, g = idx / DD;
    const float4* w  = (const float4*)(W2 + (size_t)d * TWO_D);
    const float4* h0 = (const float4*)(h + (size_t)(4 * g + 0) * TWO_D);
    const float4* h1 = (const float4*)(h + (size_t)(4 * g + 1) * TWO_D);
    const float4* h2 = (const float4*)(h + (size_t)(4 * g + 2) * TWO_D);
    const float4* h3 = (const float4*)(h + (size_t)(4 * g + 3) * TWO_D);
    float a0 = 0.f, a1 = 0.f, a2 = 0.f, a3 = 0.f;
#pragma unroll 4
    for (int i = 0; i < TWO_D / 4; ++i) {
        float4 wv = w[i];
        float4 v0 = h0[i], v1 = h1[i], v2 = h2[i], v3 = h3[i];
        a0 += wv.x * v0.x + wv.y * v0.y + wv.z * v0.z + wv.w * v0.w;
        a1 += wv.x * v1.x + wv.y * v1.y + wv.z * v1.z + wv.w * v1.w;
        a2 += wv.x * v2.x + wv.y * v2.y + wv.z * v2.z + wv.w * v2.w;
        a3 += wv.x * v3.x + wv.y * v3.y + wv.z * v3.z + wv.w * v3.w;
    }
    raw[(4 * g + 0) * DD + d] = a0;
    raw[(4 * g + 1) * DD + d] = a1;
    raw[(4 * g + 2) * DD + d] = a2;
    raw[(4 * g + 3) * DD + d] = a3;
}

// Kernel 6: out[b,:] = raw[b,:] / ||raw[b,:]||_2  (one block per b, 256 thr)
__global__ void k_norm(const float* __restrict__ raw, float* __restrict__ out) {
    int b = blockIdx.x, t = threadIdx.x;
    float v0 = raw[b * DD + t];
    float v1 = raw[b * DD + 256 + t];
    float v2 = raw[b * DD + 512 + t];
    float s = v0 * v0 + v1 * v1 + v2 * v2;
    for (int off = 32; off; off >>= 1) s += __shfl_down(s, off);
    __shared__ float sh[4];
    __shared__ float inv_s;
    int wave = t >> 6, lane = t & 63;
    if (lane == 0) sh[wave] = s;
    __syncthreads();
    if (t == 0) inv_s = 1.0f / sqrtf(sh[0] + sh[1] + sh[2] + sh[3]);
    __syncthreads();
    float inv = inv_s;
    out[b * DD + t]       = v0 * inv;
    out[b * DD + 256 + t] = v1 * inv;
    out[b * DD + 512 + t] = v2 * inv;
}

extern "C" void kernel_launch(void* const* d_in, const int* in_sizes, int n_in,
                              void* d_out, int out_size, void* d_ws, size_t ws_size,
                              hipStream_t stream) {
    const float* emb           = (const float*)d_in[0];          // (B,L,D) f32
    const float* W1            = (const float*)d_in[1];          // (2D,D) f32
    const float* W2            = (const float*)d_in[2];          // (D,2D) f32
    const unsigned int* mask   = (const unsigned int*)d_in[3];   // (B,T) bool as int32

    char* ws = (char*)d_ws;
    float* valid   = (float*)(ws + OFF_VALID);
    float* cnt     = (float*)(ws + OFF_CNT);
    float* partial = (float*)(ws + OFF_PARTIAL);
    float* mean    = (float*)(ws + OFF_MEAN);
    float* h       = (float*)(ws + OFF_H);
    float* raw     = (float*)(ws + OFF_RAW);
    float* out     = (float*)d_out;

    // k_valid: BB*LL/2 waves = 48000 waves -> 3,072,000 threads / 256 = 12000 blocks
    k_valid<<<(BB * LL / 2 * 64) / 256, 256, 0, stream>>>(mask, valid);
    k_cnt<<<BB, 256, 0, stream>>>(valid, cnt);
    dim3 g2(BB, NCH);
    k_partial<<<g2, 192, 0, stream>>>(emb, valid, partial);
    k_mean<<<(BB * DD) / 256, 256, 0, stream>>>(partial, cnt, mean);
    k_fc1<<<(TWO_D * 16) / 256, 256, 0, stream>>>(mean, W1, h);
    k_fc2<<<(DD * 16) / 256, 256, 0, stream>>>(h, W2, raw);
    k_norm<<<BB, 256, 0, stream>>>(raw, out);
}

// Round 3
// 231.777 us; speedup vs baseline: 1.0365x; 1.0365x over previous
//
#include <hip/hip_runtime.h>

// Problem constants (match reference)
#define BB 64
#define LL 1500
#define DD 768
#define TT 240000
#define BIN 160          // mask words per bin (mask arrives as int32 bools)
#define NCH 25           // L-chunks for deterministic two-stage reduce
#define LCH 60           // LL / NCH
#define TWO_D 1536
#define WPB (LCH * BIN)  // 9600 mask words per (b,chunk)

// ---------------- workspace layout (bytes) ----------------
#define OFF_PARTIAL 0          // BB*NCH*DD floats (4,915,200 B)
#define OFF_PCNT    4915200    // BB*NCH floats    (6,400 B)
#define OFF_MEAN    4921600    // BB*DD floats     (196,608 B)
#define OFF_H       5118208    // BB*TWO_D floats  (393,216 B)
#define OFF_RAW     5511424    // BB*DD floats     (196,608 B)

// Fused kernel: per (b, chunk c of 60 rows):
//  phase A: OR-reduce this chunk's 9600 mask words (coalesced uint4) -> 60 bin flags
//  phase B: build wave-uniform 64-bit valid bitmask via ballot
//  phase C: stream emb rows; counted prefix loop (fast path, loads fully
//           pipelined) or branch-free multiply-by-flag fallback (general).
// Writes partial[b,c,:] and pcnt[b,c] (no atomics -> deterministic).
__global__ __launch_bounds__(192) void k_partial(const float* __restrict__ emb,
                                                 const unsigned int* __restrict__ mask,
                                                 float* __restrict__ partial,
                                                 float* __restrict__ pcnt) {
    int b = blockIdx.x, c = blockIdx.y, t = threadIdx.x;
    int l0 = c * LCH;

    __shared__ unsigned int red[WPB / 4];   // 2400: OR of 4 consecutive words
    __shared__ unsigned int flags[LCH];     // 60: 0 == bin fully unpadded

    // phase A1: coalesced read + 4-way OR
    const uint4* mbase = (const uint4*)(mask + (size_t)b * TT + (size_t)l0 * BIN);
    for (int k = t; k < WPB / 4; k += 192) {
        uint4 v = mbase[k];
        red[k] = v.x | v.y | v.z | v.w;
    }
    __syncthreads();
    // phase A2: per-bin OR (bin i owns red[i*40 .. i*40+39])
    if (t < LCH) {
        unsigned int o = 0u;
#pragma unroll
        for (int j = 0; j < BIN / 4; ++j) o |= red[t * (BIN / 4) + j];
        flags[t] = o;
    }
    __syncthreads();

    // phase B: identical 64-bit mask in every wave (lanes 0..59 = bins)
    int lane = t & 63;
    unsigned int fv = (lane < LCH) ? flags[lane] : 1u;
    unsigned long long m = __ballot(fv == 0u);   // bit i set == row l0+i valid
    int n = __popcll(m);
    if (t == 0) pcnt[b * NCH + c] = (float)n;

    // phase C: stream embeddings, 4 consecutive d per thread (float4)
    const float* ebase = emb + ((size_t)b * LL + l0) * DD + 4 * t;
    float4 acc = {0.f, 0.f, 0.f, 0.f};
    bool prefix = (m == ((n >= 64) ? ~0ull : ((1ull << n) - 1ull)));
    if (prefix) {
        // valid rows are exactly 0..n-1: counted loop, deep load pipelining
        for (int i = 0; i < n; ++i) {
            float4 v = *(const float4*)(ebase + (size_t)i * DD);
            acc.x += v.x; acc.y += v.y; acc.z += v.z; acc.w += v.w;
        }
    } else {
        // general fallback: branch-free, flag in {0.0,1.0} multiplies exactly
        for (int i = 0; i < LCH; ++i) {
            float4 v = *(const float4*)(ebase + (size_t)i * DD);
            float f = (float)((m >> i) & 1ull);
            acc.x += f * v.x; acc.y += f * v.y; acc.z += f * v.z; acc.w += f * v.w;
        }
    }
    *(float4*)(partial + ((size_t)(b * NCH + c)) * DD + 4 * t) = acc;
}

// mean[b,d] = (sum_c partial[b,c,d]) / (sum_c pcnt[b,c])
__global__ void k_mean(const float* __restrict__ partial,
                       const float* __restrict__ pcnt,
                       float* __restrict__ mean) {
    int idx = blockIdx.x * blockDim.x + threadIdx.x;   // b*DD + d
    if (idx >= BB * DD) return;
    int b = idx / DD, d = idx % DD;
    float cnt = 0.0f;
#pragma unroll 5
    for (int c = 0; c < NCH; ++c) cnt += pcnt[b * NCH + c];
    float s = 0.0f;
#pragma unroll 5
    for (int c = 0; c < NCH; ++c) s += partial[((size_t)(b * NCH + c)) * DD + d];
    mean[idx] = s / cnt;
}

// h[b,j] = relu( sum_d mean[b,d] * W1[j,d] ), 4-wide batch tile per thread
__global__ void k_fc1(const float* __restrict__ mean,
                      const float* __restrict__ W1,
                      float* __restrict__ h) {
    int idx = blockIdx.x * blockDim.x + threadIdx.x;
    int j = idx % TWO_D, g = idx / TWO_D;
    const float4* w  = (const float4*)(W1 + (size_t)j * DD);
    const float4* m0 = (const float4*)(mean + (size_t)(4 * g + 0) * DD);
    const float4* m1 = (const float4*)(mean + (size_t)(4 * g + 1) * DD);
    const float4* m2 = (const float4*)(mean + (size_t)(4 * g + 2) * DD);
    const float4* m3 = (const float4*)(mean + (size_t)(4 * g + 3) * DD);
    float a0 = 0.f, a1 = 0.f, a2 = 0.f, a3 = 0.f;
#pragma unroll 4
    for (int i = 0; i < DD / 4; ++i) {
        float4 wv = w[i];
        float4 v0 = m0[i], v1 = m1[i], v2 = m2[i], v3 = m3[i];
        a0 += wv.x * v0.x + wv.y * v0.y + wv.z * v0.z + wv.w * v0.w;
        a1 += wv.x * v1.x + wv.y * v1.y + wv.z * v1.z + wv.w * v1.w;
        a2 += wv.x * v2.x + wv.y * v2.y + wv.z * v2.z + wv.w * v2.w;
        a3 += wv.x * v3.x + wv.y * v3.y + wv.z * v3.z + wv.w * v3.w;
    }
    h[(4 * g + 0) * TWO_D + j] = fmaxf(a0, 0.f);
    h[(4 * g + 1) * TWO_D + j] = fmaxf(a1, 0.f);
    h[(4 * g + 2) * TWO_D + j] = fmaxf(a2, 0.f);
    h[(4 * g + 3) * TWO_D + j] = fmaxf(a3, 0.f);
}

// raw[b,d] = sum_j h[b,j] * W2[d,j], 4-wide batch tile per thread
__global__ void k_fc2(const float* __restrict__ h,
                      const float* __restrict__ W2,
                      float* __restrict__ raw) {
    int idx = blockIdx.x * blockDim.x + threadIdx.x;
    int d = idx % DD, g = idx / DD;
    const float4* w  = (const float4*)(W2 + (size_t)d * TWO_D);
    const float4* h0 = (const float4*)(h + (size_t)(4 * g + 0) * TWO_D);
    const float4* h1 = (const float4*)(h + (size_t)(4 * g + 1) * TWO_D);
    const float4* h2 = (const float4*)(h + (size_t)(4 * g + 2) * TWO_D);
    const float4* h3 = (const float4*)(h + (size_t)(4 * g + 3) * TWO_D);
    float a0 = 0.f, a1 = 0.f, a2 = 0.f, a3 = 0.f;
#pragma unroll 4
    for (int i = 0; i < TWO_D / 4; ++i) {
        float4 wv = w[i];
        float4 v0 = h0[i], v1 = h1[i], v2 = h2[i], v3 = h3[i];
        a0 += wv.x * v0.x + wv.y * v0.y + wv.z * v0.z + wv.w * v0.w;
        a1 += wv.x * v1.x + wv.y * v1.y + wv.z * v1.z + wv.w * v1.w;
        a2 += wv.x * v2.x + wv.y * v2.y + wv.z * v2.z + wv.w * v2.w;
        a3 += wv.x * v3.x + wv.y * v3.y + wv.z * v3.z + wv.w * v3.w;
    }
    raw[(4 * g + 0) * DD + d] = a0;
    raw[(4 * g + 1) * DD + d] = a1;
    raw[(4 * g + 2) * DD + d] = a2;
    raw[(4 * g + 3) * DD + d] = a3;
}

// out[b,:] = raw[b,:] / ||raw[b,:]||_2  (one block per b, 256 threads)
__global__ void k_norm(const float* __restrict__ raw, float* __restrict__ out) {
    int b = blockIdx.x, t = threadIdx.x;
    float v0 = raw[b * DD + t];
    float v1 = raw[b * DD + 256 + t];
    float v2 = raw[b * DD + 512 + t];
    float s = v0 * v0 + v1 * v1 + v2 * v2;
    for (int off = 32; off; off >>= 1) s += __shfl_down(s, off);
    __shared__ float sh[4];
    __shared__ float inv_s;
    int wave = t >> 6, lane = t & 63;
    if (lane == 0) sh[wave] = s;
    __syncthreads();
    if (t == 0) inv_s = 1.0f / sqrtf(sh[0] + sh[1] + sh[2] + sh[3]);
    __syncthreads();
    float inv = inv_s;
    out[b * DD + t]       = v0 * inv;
    out[b * DD + 256 + t] = v1 * inv;
    out[b * DD + 512 + t] = v2 * inv;
}

extern "C" void kernel_launch(void* const* d_in, const int* in_sizes, int n_in,
                              void* d_out, int out_size, void* d_ws, size_t ws_size,
                              hipStream_t stream) {
    const float* emb         = (const float*)d_in[0];          // (B,L,D) f32
    const float* W1          = (const float*)d_in[1];          // (2D,D) f32
    const float* W2          = (const float*)d_in[2];          // (D,2D) f32
    const unsigned int* mask = (const unsigned int*)d_in[3];   // (B,T) bool as int32

    char* ws = (char*)d_ws;
    float* partial = (float*)(ws + OFF_PARTIAL);
    float* pcnt    = (float*)(ws + OFF_PCNT);
    float* mean    = (float*)(ws + OFF_MEAN);
    float* h       = (float*)(ws + OFF_H);
    float* raw     = (float*)(ws + OFF_RAW);
    float* out     = (float*)d_out;

    dim3 g2(BB, NCH);
    k_partial<<<g2, 192, 0, stream>>>(emb, mask, partial, pcnt);
    k_mean<<<(BB * DD) / 256, 256, 0, stream>>>(partial, pcnt, mean);
    k_fc1<<<(TWO_D * 16) / 256, 256, 0, stream>>>(mean, W1, h);
    k_fc2<<<(DD * 16) / 256, 256, 0, stream>>>(h, W2, raw);
    k_norm<<<BB, 256, 0, stream>>>(raw, out);
}

// Round 4
// 231.140 us; speedup vs baseline: 1.0394x; 1.0028x over previous
//
#include <hip/hip_runtime.h>

// Problem constants (match reference)
#define BB 64
#define LL 1500
#define DD 768
#define TT 240000
#define BIN 160          // mask words per bin (mask arrives as int32 bools)
#define NCH 25           // L-chunks for deterministic two-stage reduce
#define LCH 60           // LL / NCH
#define TWO_D 1536
#define WPB (LCH * BIN)  // 9600 mask words per (b,chunk)

// ---------------- workspace layout (bytes) ----------------
#define OFF_PARTIAL 0          // BB*NCH*DD floats (4,915,200 B)
#define OFF_PCNT    4915200    // BB*NCH floats    (6,400 B)
#define OFF_MEAN    4921600    // BB*DD floats     (196,608 B)
#define OFF_H       5118208    // BB*TWO_D floats  (393,216 B)
#define OFF_RAW     5511424    // BB*DD floats     (196,608 B)

// Fused kernel: per (b, chunk c of 60 rows):
//  phase A: OR-reduce this chunk's 9600 mask words -> 60 bin flags (LDS, padded)
//  phase B: wave-uniform 64-bit valid bitmask via ballot; n==0 -> early-out
//  phase C: stream 60 emb rows, FIXED-TRIP loop unrolled x10, branch-free
//           flag-FMA (f in {0,1} -> exact). 10 loads in flight per wave.
__global__ __launch_bounds__(192) void k_partial(const float* __restrict__ emb,
                                                 const unsigned int* __restrict__ mask,
                                                 float* __restrict__ partial,
                                                 float* __restrict__ pcnt) {
    int b = blockIdx.x, c = blockIdx.y, t = threadIdx.x;
    int l0 = c * LCH;

    // padded: 40 payload words + 1 pad per bin -> phase A2 reads ~conflict-free
    __shared__ unsigned int red[LCH * 41];  // 2460 words
    __shared__ unsigned int flags[LCH];     // 0 == bin fully unpadded

    // phase A1: coalesced uint4 read + 4-way OR; write with per-bin pad skip
    const uint4* mbase = (const uint4*)(mask + (size_t)b * TT + (size_t)l0 * BIN);
    for (int k = t; k < WPB / 4; k += 192) {
        uint4 v = mbase[k];
        red[k + k / 40] = v.x | v.y | v.z | v.w;
    }
    __syncthreads();
    // phase A2: per-bin OR (bin i owns red[i*41 .. i*41+39])
    if (t < LCH) {
        unsigned int o = 0u;
#pragma unroll
        for (int j = 0; j < BIN / 4; ++j) o |= red[t * 41 + j];
        flags[t] = o;
    }
    __syncthreads();

    // phase B: identical 64-bit mask in every wave (lanes 0..59 = bins)
    int lane = t & 63;
    unsigned int fv = (lane < LCH) ? flags[lane] : 1u;
    unsigned long long m = __ballot(fv == 0u);   // bit i set == row l0+i valid
    int n = __popcll(m);
    if (t == 0) pcnt[b * NCH + c] = (float)n;

    float* pout = partial + ((size_t)(b * NCH + c)) * DD + 4 * t;
    if (n == 0) {                       // block-uniform: skip emb read entirely
        float4 z = {0.f, 0.f, 0.f, 0.f};
        *(float4*)pout = z;
        return;
    }

    // phase C: 4 consecutive d per thread (float4), 6 x unroll-10 batches
    const float* ebase = emb + ((size_t)b * LL + l0) * DD + 4 * t;
    float4 acc = {0.f, 0.f, 0.f, 0.f};
    for (int i0 = 0; i0 < LCH; i0 += 10) {
#pragma unroll
        for (int j = 0; j < 10; ++j) {
            int i = i0 + j;
            float4 v = *(const float4*)(ebase + (size_t)i * DD);
            float f = (float)((m >> i) & 1ull);
            acc.x = fmaf(f, v.x, acc.x);
            acc.y = fmaf(f, v.y, acc.y);
            acc.z = fmaf(f, v.z, acc.z);
            acc.w = fmaf(f, v.w, acc.w);
        }
    }
    *(float4*)pout = acc;
}

// mean[b,d] = (sum_c partial[b,c,d]) / (sum_c pcnt[b,c])
__global__ void k_mean(const float* __restrict__ partial,
                       const float* __restrict__ pcnt,
                       float* __restrict__ mean) {
    int idx = blockIdx.x * blockDim.x + threadIdx.x;   // b*DD + d
    if (idx >= BB * DD) return;
    int b = idx / DD, d = idx % DD;
    float cnt = 0.0f;
#pragma unroll 5
    for (int c = 0; c < NCH; ++c) cnt += pcnt[b * NCH + c];
    float s = 0.0f;
#pragma unroll 5
    for (int c = 0; c < NCH; ++c) s += partial[((size_t)(b * NCH + c)) * DD + d];
    mean[idx] = s / cnt;
}

// h[b,j] = relu( sum_d mean[b,d] * W1[j,d] ), 4-wide batch tile per thread
__global__ void k_fc1(const float* __restrict__ mean,
                      const float* __restrict__ W1,
                      float* __restrict__ h) {
    int idx = blockIdx.x * blockDim.x + threadIdx.x;
    int j = idx % TWO_D, g = idx / TWO_D;
    const float4* w  = (const float4*)(W1 + (size_t)j * DD);
    const float4* m0 = (const float4*)(mean + (size_t)(4 * g + 0) * DD);
    const float4* m1 = (const float4*)(mean + (size_t)(4 * g + 1) * DD);
    const float4* m2 = (const float4*)(mean + (size_t)(4 * g + 2) * DD);
    const float4* m3 = (const float4*)(mean + (size_t)(4 * g + 3) * DD);
    float a0 = 0.f, a1 = 0.f, a2 = 0.f, a3 = 0.f;
#pragma unroll 4
    for (int i = 0; i < DD / 4; ++i) {
        float4 wv = w[i];
        float4 v0 = m0[i], v1 = m1[i], v2 = m2[i], v3 = m3[i];
        a0 += wv.x * v0.x + wv.y * v0.y + wv.z * v0.z + wv.w * v0.w;
        a1 += wv.x * v1.x + wv.y * v1.y + wv.z * v1.z + wv.w * v1.w;
        a2 += wv.x * v2.x + wv.y * v2.y + wv.z * v2.z + wv.w * v2.w;
        a3 += wv.x * v3.x + wv.y * v3.y + wv.z * v3.z + wv.w * v3.w;
    }
    h[(4 * g + 0) * TWO_D + j] = fmaxf(a0, 0.f);
    h[(4 * g + 1) * TWO_D + j] = fmaxf(a1, 0.f);
    h[(4 * g + 2) * TWO_D + j] = fmaxf(a2, 0.f);
    h[(4 * g + 3) * TWO_D + j] = fmaxf(a3, 0.f);
}

// raw[b,d] = sum_j h[b,j] * W2[d,j], 4-wide batch tile per thread
__global__ void k_fc2(const float* __restrict__ h,
                      const float* __restrict__ W2,
                      float* __restrict__ raw) {
    int idx = blockIdx.x * blockDim.x + threadIdx.x;
    int d = idx % DD, g = idx / DD;
    const float4* w  = (const float4*)(W2 + (size_t)d * TWO_D);
    const float4* h0 = (const float4*)(h + (size_t)(4 * g + 0) * TWO_D);
    const float4* h1 = (const float4*)(h + (size_t)(4 * g + 1) * TWO_D);
    const float4* h2 = (const float4*)(h + (size_t)(4 * g + 2) * TWO_D);
    const float4* h3 = (const float4*)(h + (size_t)(4 * g + 3) * TWO_D);
    float a0 = 0.f, a1 = 0.f, a2 = 0.f, a3 = 0.f;
#pragma unroll 4
    for (int i = 0; i < TWO_D / 4; ++i) {
        float4 wv = w[i];
        float4 v0 = h0[i], v1 = h1[i], v2 = h2[i], v3 = h3[i];
        a0 += wv.x * v0.x + wv.y * v0.y + wv.z * v0.z + wv.w * v0.w;
        a1 += wv.x * v1.x + wv.y * v1.y + wv.z * v1.z + wv.w * v1.w;
        a2 += wv.x * v2.x + wv.y * v2.y + wv.z * v2.z + wv.w * v2.w;
        a3 += wv.x * v3.x + wv.y * v3.y + wv.z * v3.z + wv.w * v3.w;
    }
    raw[(4 * g + 0) * DD + d] = a0;
    raw[(4 * g + 1) * DD + d] = a1;
    raw[(4 * g + 2) * DD + d] = a2;
    raw[(4 * g + 3) * DD + d] = a3;
}

// out[b,:] = raw[b,:] / ||raw[b,:]||_2  (one block per b, 256 threads)
__global__ void k_norm(const float* __restrict__ raw, float* __restrict__ out) {
    int b = blockIdx.x, t = threadIdx.x;
    float v0 = raw[b * DD + t];
    float v1 = raw[b * DD + 256 + t];
    float v2 = raw[b * DD + 512 + t];
    float s = v0 * v0 + v1 * v1 + v2 * v2;
    for (int off = 32; off; off >>= 1) s += __shfl_down(s, off);
    __shared__ float sh[4];
    __shared__ float inv_s;
    int wave = t >> 6, lane = t & 63;
    if (lane == 0) sh[wave] = s;
    __syncthreads();
    if (t == 0) inv_s = 1.0f / sqrtf(sh[0] + sh[1] + sh[2] + sh[3]);
    __syncthreads();
    float inv = inv_s;
    out[b * DD + t]       = v0 * inv;
    out[b * DD + 256 + t] = v1 * inv;
    out[b * DD + 512 + t] = v2 * inv;
}

extern "C" void kernel_launch(void* const* d_in, const int* in_sizes, int n_in,
                              void* d_out, int out_size, void* d_ws, size_t ws_size,
                              hipStream_t stream) {
    const float* emb         = (const float*)d_in[0];          // (B,L,D) f32
    const float* W1          = (const float*)d_in[1];          // (2D,D) f32
    const float* W2          = (const float*)d_in[2];          // (D,2D) f32
    const unsigned int* mask = (const unsigned int*)d_in[3];   // (B,T) bool as int32

    char* ws = (char*)d_ws;
    float* partial = (float*)(ws + OFF_PARTIAL);
    float* pcnt    = (float*)(ws + OFF_PCNT);
    float* mean    = (float*)(ws + OFF_MEAN);
    float* h       = (float*)(ws + OFF_H);
    float* raw     = (float*)(ws + OFF_RAW);
    float* out     = (float*)d_out;

    dim3 g2(BB, NCH);
    k_partial<<<g2, 192, 0, stream>>>(emb, mask, partial, pcnt);
    k_mean<<<(BB * DD) / 256, 256, 0, stream>>>(partial, pcnt, mean);
    k_fc1<<<(TWO_D * 16) / 256, 256, 0, stream>>>(mean, W1, h);
    k_fc2<<<(DD * 16) / 256, 256, 0, stream>>>(h, W2, raw);
    k_norm<<<BB, 256, 0, stream>>>(raw, out);
}